// Round 17
// baseline (3921.763 us; speedup 1.0000x reference)
//
#include <hip/hip_runtime.h>
#include <math.h>

#define DD 128
#define HH 256
#define NS 300
#define BB 512
#define NPO (301*64)

__device__ __forceinline__ float tsf(int t){ return (float)((double)t*(1.0/(double)NS)); }

__device__ __forceinline__ float wave_red(float v){
#pragma unroll
  for(int o=32;o>0;o>>=1) v += __shfl_down(v,o);
  return v;
}
__device__ __forceinline__ float fma4(float4 a, float4 b, float acc){
  acc = fmaf(a.x,b.x,acc); acc = fmaf(a.y,b.y,acc);
  acc = fmaf(a.z,b.z,acc); acc = fmaf(a.w,b.w,acc); return acc;
}

// ---- pre1: identity flag + (general) Gauss-Jordan inverse -> SIT = sigma^-T
__global__ __launch_bounds__(256) void k_pre1(
    const float* __restrict__ sigma,
    float* __restrict__ SIT, float* __restrict__ AUG, int* __restrict__ FLG)
{
  const int j = threadIdx.x;
  __shared__ int s_ok; __shared__ int s_p; __shared__ float s_fac[DD];
  if (j == 0) s_ok = 1;
  __syncthreads();
  bool ok = true;
  for (int idx = j; idx < DD*DD; idx += 256) {
    const int r = idx >> 7, c = idx & 127;
    if (sigma[idx] != (r==c ? 1.f : 0.f)) ok = false;
  }
  if (!ok) s_ok = 0;
  __syncthreads();
  const bool ident = (s_ok != 0);
  if (j == 0) *FLG = ident ? 1 : 0;
  if (ident) {
    for (int idx = j; idx < DD*DD; idx += 256) {
      const int r = idx >> 7, c = idx & 127;
      SIT[idx] = (r==c) ? 1.f : 0.f;
    }
    return;
  }
  for (int idx = j; idx < DD*256; idx += 256) {
    const int r = idx >> 8, c = idx & 255;
    AUG[idx] = (c < DD) ? sigma[r*DD + c] : ((c-DD)==r ? 1.f : 0.f);
  }
  __syncthreads();
  for (int c = 0; c < DD; ++c) {
    if (j == 0) {
      int p = c; float best = fabsf(AUG[c*256 + c]);
      for (int r2 = c+1; r2 < DD; ++r2) {
        const float v = fabsf(AUG[r2*256 + c]);
        if (v > best) { best = v; p = r2; }
      }
      s_p = p;
    }
    __syncthreads();
    const int p = s_p;
    if (p != c) {
      const float tmp = AUG[c*256 + j];
      AUG[c*256 + j] = AUG[p*256 + j];
      AUG[p*256 + j] = tmp;
    }
    __syncthreads();
    const float pd = AUG[c*256 + c];
    const float rowv = AUG[c*256 + j];
    __syncthreads();
    AUG[c*256 + j] = rowv / pd;
    if (j < DD) s_fac[j] = (j == c) ? 0.f : AUG[j*256 + c];
    __syncthreads();
    const float prj = AUG[c*256 + j];
    for (int r2 = 0; r2 < DD; ++r2) {
      if (r2 != c) AUG[r2*256 + j] -= s_fac[r2] * prj;
    }
    __syncthreads();
  }
  for (int idx = j; idx < DD*DD; idx += 256) {
    const int j2 = idx >> 7, k = idx & 127;
    SIT[idx] = AUG[k*256 + DD + j2];   // sigma^-T[j2][k]
  }
}

// ---- pre2: quad-interleaved coalesced layouts + W2A^T = W2@A^T + Ab2 = A@b2
__global__ __launch_bounds__(256) void k_pre2(
    const float* __restrict__ W1, const float* __restrict__ W2,
    const float* __restrict__ A, const float* __restrict__ P,
    const float* __restrict__ Q, const float* __restrict__ sigma,
    const float* __restrict__ b2, const float* __restrict__ SIT,
    const int* __restrict__ FLG,
    float* __restrict__ W1L, float* __restrict__ W2L,
    float* __restrict__ AL, float* __restrict__ PL,
    float* __restrict__ ML, float* __restrict__ SL,
    float* __restrict__ STL, float* __restrict__ QL,
    float* __restrict__ W2ATL, float* __restrict__ Ab2,
    float* __restrict__ SGC)
{
  const int g = blockIdx.x*256 + threadIdx.x;
  const int gs = gridDim.x*256;
  const bool ident = (*FLG != 0);
  for (int idx = g; idx < 32*256; idx += gs) {
    const int k4 = idx >> 8, hj = idx & 255;
#pragma unroll
    for (int j = 0; j < 4; ++j)
      W1L[idx*4 + j] = W1[(4*k4 + 1 + j)*HH + hj];
  }
  for (int idx = g; idx < 64*128; idx += gs) {
    const int k4 = idx >> 7, i = idx & 127;
#pragma unroll
    for (int j = 0; j < 4; ++j)
      W2L[idx*4 + j] = W2[(4*k4 + j)*DD + i];
  }
  for (int idx = g; idx < 32*128; idx += gs) {
    const int k4 = idx >> 7, i = idx & 127;
#pragma unroll
    for (int j = 0; j < 4; ++j) {
      AL [idx*4 + j] = A[i*DD + 4*k4 + j];
      PL [idx*4 + j] = P[i*DD + 4*k4 + j];
      QL [idx*4 + j] = Q[i*DD + 4*k4 + j];
      STL[idx*4 + j] = sigma[i*DD + 4*k4 + j];
      SL [idx*4 + j] = sigma[(4*k4 + j)*DD + i];
      float m;
      if (ident) m = -A[i*DD + 4*k4 + j];
      else {
        float acc = 0.f;
        for (int jj = 0; jj < DD; ++jj)
          acc = fmaf(A[i*DD + jj], SIT[jj*DD + 4*k4 + j], acc);
        m = -acc;
      }
      ML[idx*4 + j] = m;
    }
  }
  // W2AT[k][i] = sum_m W2[k][m]*A[i][m], quad-interleaved like W2L
  for (int idx = g; idx < 64*128; idx += gs) {
    const int k4 = idx >> 7, i2 = idx & 127;
    const float4* arow = (const float4*)(A + (size_t)i2*DD);
#pragma unroll
    for (int j = 0; j < 4; ++j) {
      const float4* wrow = (const float4*)(W2 + (size_t)(4*k4 + j)*DD);
      float acc = 0.f;
      for (int m = 0; m < 32; ++m) acc = fma4(wrow[m], arow[m], acc);
      W2ATL[idx*4 + j] = acc;
    }
  }
  for (int idx = g; idx < DD; idx += gs) {
    float acc = 0.f;
    for (int k = 0; k < DD; ++k) acc = fmaf(A[idx*DD + k], b2[k], acc);
    Ab2[idx] = acc;
  }
  for (int idx = g; idx < DD*DD; idx += gs) {
    const int i2 = idx >> 7, k = idx & 127;
    SGC[idx] = sigma[k*DD + i2];
  }
}

// ---- identity-sigma rollout: 128 blocks x 512 threads, 4 rows/block.
// 4 barriers/step. W2A^T fold with every scheduling region capped at an
// r13-proven register shape (single-stream or dual-stream, <=12 acc),
// separated by sched_barrier(0) so the compiler cannot merge load pipelines:
//   A{L1}  B{tanh}
//   C{C1 h@W2 | C2 h@W2A^T | C3 A@x,A@nz,P@x}   (3 sequential passes)
//   D{owner: u, U, mm, TL, x-update, lw, noise prefetch}
__global__ __launch_bounds__(512) void k_roll_id4w3(
    const float* __restrict__ x0,
    const float* __restrict__ W1, const float* __restrict__ b1,
    const float* __restrict__ b2, const float* __restrict__ noises,
    const float* __restrict__ W1L, const float* __restrict__ W2L,
    const float* __restrict__ W2ATL, const float* __restrict__ AL,
    const float* __restrict__ PL, const float* __restrict__ QL,
    const float* __restrict__ Ab2, const int* __restrict__ FLG,
    float* __restrict__ U, float* __restrict__ TL,
    float* __restrict__ TGT, float* __restrict__ WGT)
{
  if (*FLG == 0) return;   // general sigma handled by k_roll_gen
  __shared__ __align__(16) float xs[4][128];
  __shared__ __align__(16) float hs[4][256];
  __shared__ __align__(16) float noi[4][128];
  __shared__ __align__(16) float p2[2][4][256];
  __shared__ __align__(16) float pNv[4][4][128];
  __shared__ __align__(16) float pNa[4][4][128];
  __shared__ __align__(16) float pAx[4][4][128];
  __shared__ __align__(16) float pPx[4][4][128];
  __shared__ __align__(16) float pNz[4][4][128];
  __shared__ float red[16];

  const float4* W1L4 = (const float4*)W1L;
  const float4* W2L4 = (const float4*)W2L;
  const float4* WAT4 = (const float4*)W2ATL;
  const float4* AL4  = (const float4*)AL;
  const float4* PL4  = (const float4*)PL;
  const float4* QL4  = (const float4*)QL;
  float4* xs4  = (float4*)&xs[0][0];    // row r at quad offset r*32
  float4* hs4  = (float4*)&hs[0][0];    // row r at quad offset r*64
  float4* noi4 = (float4*)&noi[0][0];

  const int tid = threadIdx.x;
  const int hj = tid & 255, hg = tid >> 8;   // layer-1 mapping
  const int i  = tid & 127, q  = tid >> 7;   // matvec quarter AND owned row
  const int wid = tid >> 6;
  const int b0 = blockIdx.x * 4;
  const float w1t = (hg == 0) ? W1[hj] : 0.f;
  const float b1c = b1[hj];
  const float b2i = b2[i];
  const float ab2i = Ab2[i];

  xs[q][i] = x0[i];
  noi[q][i] = noises[(size_t)(b0 + q)*DD + i];   // noise[t=0]

  float lwloc = 0.f;

  for (int t = 0; t <= NS; ++t) {
    __syncthreads();                                   // [TOP] xs, noi ready
    const float t0 = tsf(t);
    const float dt = tsf(t+1) - t0;
    const float sdt = sqrtf(dt);

    // --- phase A: L1 half-dot, 4 rows per W1 load (r13-proven shape)
    {
      float a0 = t0*w1t, a1 = t0*w1t, a2 = t0*w1t, a3 = t0*w1t;
#pragma unroll
      for (int m = 0; m < 16; ++m) {
        const float4 w = W1L4[(hg*16 + m)*256 + hj];
        a0 = fma4(w, xs4[0*32 + hg*16 + m], a0);
        a1 = fma4(w, xs4[1*32 + hg*16 + m], a1);
        a2 = fma4(w, xs4[2*32 + hg*16 + m], a2);
        a3 = fma4(w, xs4[3*32 + hg*16 + m], a3);
      }
      p2[hg][0][hj] = a0; p2[hg][1][hj] = a1;
      p2[hg][2][hj] = a2; p2[hg][3][hj] = a3;
    }
    __syncthreads();                                   // [A->B]
    // --- phase B: tanh (rows hg and hg+2 per thread)
    {
#pragma unroll
      for (int rr = 0; rr < 2; ++rr) {
        const int r = hg + 2*rr;
        hs[r][hj] = tanhf(p2[0][r][hj] + p2[1][r][hj] + b1c);
      }
    }
    __syncthreads();                                   // [B->C]
    // --- phase C pass 1: h@W2 quarter-dot (r13 phase-C shape: 4 acc, 1 stream)
    {
      float c[4] = {0,0,0,0};
#pragma unroll
      for (int m = 0; m < 16; ++m) {
        const float4 w2 = W2L4[(q*16 + m)*128 + i];
#pragma unroll
        for (int r = 0; r < 4; ++r)
          c[r] = fma4(w2, hs4[r*64 + q*16 + m], c[r]);
      }
#pragma unroll
      for (int r = 0; r < 4; ++r) pNv[q][r][i] = c[r];
    }
    __builtin_amdgcn_sched_barrier(0);
    // --- phase C pass 2: h@W2A^T quarter-dot (same proven shape)
    {
      float d[4] = {0,0,0,0};
#pragma unroll
      for (int m = 0; m < 16; ++m) {
        const float4 wa = WAT4[(q*16 + m)*128 + i];
#pragma unroll
        for (int r = 0; r < 4; ++r)
          d[r] = fma4(wa, hs4[r*64 + q*16 + m], d[r]);
      }
#pragma unroll
      for (int r = 0; r < 4; ++r) pNa[q][r][i] = d[r];
    }
    __builtin_amdgcn_sched_barrier(0);
    // --- phase C pass 3: A@x, A@nz, P@x (r13 phase-E shape: 12 acc, 2 streams)
    {
      float ax[4] = {0,0,0,0}, an[4] = {0,0,0,0}, py[4] = {0,0,0,0};
#pragma unroll
      for (int m = 0; m < 8; ++m) {
        const float4 av = AL4[(q*8 + m)*128 + i];
        const float4 pv = PL4[(q*8 + m)*128 + i];
#pragma unroll
        for (int r = 0; r < 4; ++r) {
          const float4 xv = xs4[r*32 + q*8 + m];
          const float4 nv = noi4[r*32 + q*8 + m];
          ax[r] = fma4(av, xv, ax[r]);
          an[r] = fma4(av, nv, an[r]);
          py[r] = fma4(pv, xv, py[r]);
        }
      }
#pragma unroll
      for (int r = 0; r < 4; ++r) {
        pAx[q][r][i] = ax[r];
        pNz[q][r][i] = an[r];
        pPx[q][r][i] = py[r];
      }
    }
    __syncthreads();                                   // [C->D]
    // --- phase D: owner (i, row q): all combines, stores, update, prefetch
    {
      const float nv = pNv[0][q][i] + pNv[1][q][i]
                     + pNv[2][q][i] + pNv[3][q][i] + b2i;
      const float u_reg = -nv;
      U[((size_t)t*BB + b0 + q)*DD + i] = u_reg;
      if (t < NS) {
        const float nvA = pNa[0][q][i] + pNa[1][q][i]
                        + pNa[2][q][i] + pNa[3][q][i];
        const float anz = pNz[0][q][i] + pNz[1][q][i]
                        + pNz[2][q][i] + pNz[3][q][i];
        const float xa  = pAx[0][q][i] + pAx[1][q][i]
                        + pAx[2][q][i] + pAx[3][q][i];
        const float yy  = pPx[0][q][i] + pPx[1][q][i]
                        + pPx[2][q][i] + pPx[3][q][i];
        const float nz = noi[q][i];
        // mm = -(A@wv); wv = sdt*nz + dt*u; A@u = -(h@W2A^T + A@b2)
        const float mm = -sdt*anz + dt*(nvA + ab2i);
        TL[(size_t)(t+1)*(BB*DD) + (size_t)(b0 + q)*DD + i] = dt*yy + mm;
        const float xo = xs[q][i];
        xs[q][i] = xo + (xa + u_reg)*dt + sdt*nz;
        lwloc += sdt*u_reg*nz - dt*(0.5f*u_reg*u_reg + 0.5f*xo*yy);
        if (t + 1 < NS)
          noi[q][i] = noises[((size_t)(t+1)*BB + b0 + q)*DD + i];
      }
    }
    if (t == NS) break;
  }
  // --- epilogue: TGT = x_NS @ Q^T, WGT = exp(lw - 0.5 x^T Q x)
  __syncthreads();
  {
    float g[4] = {0,0,0,0};
#pragma unroll
    for (int m = 0; m < 8; ++m) {
      const float4 qv = QL4[(q*8 + m)*128 + i];
#pragma unroll
      for (int r = 0; r < 4; ++r)
        g[r] = fma4(qv, xs4[r*32 + q*8 + m], g[r]);
    }
#pragma unroll
    for (int r = 0; r < 4; ++r) pAx[q][r][i] = g[r];
  }
  __syncthreads();
  float qloc;
  {
    const float tt = pAx[0][q][i] + pAx[1][q][i] + pAx[2][q][i] + pAx[3][q][i];
    TGT[(b0 + q)*DD + i] = tt;
    qloc = xs[q][i]*tt;
  }
  const float rq = wave_red(qloc);
  const float rl = wave_red(lwloc);
  if ((tid & 63) == 0) { red[wid] = rq; red[8 + wid] = rl; }
  __syncthreads();
  if (tid < 4) {
    const float qf = red[2*tid] + red[2*tid + 1];
    const float lw = red[8 + 2*tid] + red[8 + 2*tid + 1];
    WGT[b0 + tid] = expf(lw - 0.5f*qf);
  }
}

// ---- general-sigma rollout (round-10 structure, guarded; runs only if !ident)
__global__ __launch_bounds__(512) void k_roll_gen(
    const float* __restrict__ x0,
    const float* __restrict__ W1, const float* __restrict__ b1,
    const float* __restrict__ b2, const float* __restrict__ noises,
    const float* __restrict__ W1L, const float* __restrict__ W2L,
    const float* __restrict__ AL, const float* __restrict__ PL,
    const float* __restrict__ ML, const float* __restrict__ SL,
    const float* __restrict__ STL, const float* __restrict__ QL,
    const int* __restrict__ FLG,
    float* __restrict__ U, float* __restrict__ TL,
    float* __restrict__ TGT, float* __restrict__ WGT)
{
  if (*FLG != 0) return;
  __shared__ __align__(16) float xs[2][128];
  __shared__ __align__(16) float hs[2][256];
  __shared__ __align__(16) float noi[2][128];
  __shared__ __align__(16) float nvs[2][128];
  __shared__ __align__(16) float uu[2][128];
  __shared__ __align__(16) float wv[2][128];
  __shared__ __align__(16) float p2[2][2][256];
  __shared__ __align__(16) float p4[4][2][128];
  __shared__ __align__(16) float pm3[3][4][2][128];
  __shared__ float red[16];

  const float4* W1L4 = (const float4*)W1L;
  const float4* W2L4 = (const float4*)W2L;
  const float4* AL4  = (const float4*)AL;
  const float4* PL4  = (const float4*)PL;
  const float4* ML4  = (const float4*)ML;
  const float4* SL4  = (const float4*)SL;
  const float4* STL4 = (const float4*)STL;
  const float4* QL4  = (const float4*)QL;
  float4* xs4  = (float4*)&xs[0][0];
  float4* hs4  = (float4*)&hs[0][0];
  float4* wv4  = (float4*)&wv[0][0];
  float4* nvs4 = (float4*)&nvs[0][0];
  float4* uu4  = (float4*)&uu[0][0];
  float4* noi4 = (float4*)&noi[0][0];
  float* p2f = &p2[0][0][0];
  float* p4f = &p4[0][0][0];
  float* pA  = &pm3[0][0][0][0];
  float* pP  = &pm3[1][0][0][0];
  float* pM  = &pm3[2][0][0][0];

  const int tid = threadIdx.x;
  const int hj = tid & 255, hg = tid >> 8;
  const int i  = tid & 127, q  = tid >> 7;
  const int wid = tid >> 6;
  const int b0 = blockIdx.x * 2;
  const float w1t = (hg == 0) ? W1[hj] : 0.f;
  const float b1c = b1[hj];
  const float b2i = b2[i];

  if (tid < 256) xs[tid >> 7][tid & 127] = x0[tid & 127];

  float lwloc = 0.f, u_reg = 0.f, nz = 0.f;

  for (int t = 0; t <= NS; ++t) {
    __syncthreads();
    const float t0 = tsf(t);
    const float dt = tsf(t+1) - t0;
    const float sdt = sqrtf(dt);
    nz = 0.f;
    if (q < 2 && t < NS) {
      nz = noises[((size_t)t*BB + b0 + q)*DD + i];
      noi[q][i] = nz;
    }
    {
      float a0 = t0*w1t, a1 = t0*w1t;
#pragma unroll
      for (int m = 0; m < 16; ++m) {
        const float4 w = W1L4[(hg*16 + m)*256 + hj];
        a0 = fma4(w, xs4[hg*16 + m], a0);
        a1 = fma4(w, xs4[32 + hg*16 + m], a1);
      }
      p2[hg][0][hj] = a0; p2[hg][1][hj] = a1;
    }
    __syncthreads();
    {
      const int rr = tid >> 8, cc = tid & 255;
      hs[rr][cc] = tanhf(p2[0][rr][cc] + p2[1][rr][cc] + b1c);
    }
    __syncthreads();
    {
      float c0 = 0.f, c1 = 0.f;
#pragma unroll
      for (int m = 0; m < 16; ++m) {
        const float4 w2 = W2L4[(q*16 + m)*128 + i];
        c0 = fma4(w2, hs4[q*16 + m], c0);
        c1 = fma4(w2, hs4[64 + q*16 + m], c1);
      }
      p4[q][0][i] = c0; p4[q][1][i] = c1;
    }
    __syncthreads();
    if (q < 2) {
      nvs[q][i] = p4[0][q][i] + p4[1][q][i] + p4[2][q][i] + p4[3][q][i] + b2i;
    }
    __syncthreads();
    {
      float s0 = 0.f, s1 = 0.f;
#pragma unroll
      for (int m = 0; m < 8; ++m) {
        const float4 gv = SL4[(q*8 + m)*128 + i];
        s0 = fma4(gv, nvs4[q*8 + m], s0);
        s1 = fma4(gv, nvs4[32 + q*8 + m], s1);
      }
      pA[q*256 + i] = s0; pA[q*256 + 128 + i] = s1;
    }
    __syncthreads();
    if (q < 2) {
      u_reg = -(pA[q*128 + i] + pA[256 + q*128 + i]
              + pA[512 + q*128 + i] + pA[768 + q*128 + i]);
      uu[q][i] = u_reg;
      U[((size_t)t*BB + b0 + q)*DD + i] = u_reg;
      wv[q][i] = sdt*nz + dt*u_reg;
      if (t < NS) lwloc += sdt*u_reg*nz - 0.5f*dt*u_reg*u_reg;
    }
    if (t == NS) break;
    __syncthreads();
    {
      float aA0=0,aA1=0,aP0=0,aP1=0,aM0=0,aM1=0;
#pragma unroll
      for (int m = 0; m < 8; ++m) {
        const float4 av = AL4[(q*8 + m)*128 + i];
        const float4 pv = PL4[(q*8 + m)*128 + i];
        const float4 mv = ML4[(q*8 + m)*128 + i];
        const float4 x0v = xs4[q*8 + m];
        const float4 x1v = xs4[32 + q*8 + m];
        const float4 w0v = wv4[q*8 + m];
        const float4 w1v = wv4[32 + q*8 + m];
        aA0 = fma4(av, x0v, aA0); aA1 = fma4(av, x1v, aA1);
        aP0 = fma4(pv, x0v, aP0); aP1 = fma4(pv, x1v, aP1);
        aM0 = fma4(mv, w0v, aM0); aM1 = fma4(mv, w1v, aM1);
      }
      pA[q*256 + i] = aA0; pA[q*256 + 128 + i] = aA1;
      pP[q*256 + i] = aP0; pP[q*256 + 128 + i] = aP1;
      pM[q*256 + i] = aM0; pM[q*256 + 128 + i] = aM1;
      float su0=0,su1=0,sn0=0,sn1=0;
#pragma unroll
      for (int m = 0; m < 8; ++m) {
        const float4 sv = STL4[(q*8 + m)*128 + i];
        su0 = fma4(sv, uu4[q*8 + m],  su0);
        su1 = fma4(sv, uu4[32 + q*8 + m], su1);
        sn0 = fma4(sv, noi4[q*8 + m], sn0);
        sn1 = fma4(sv, noi4[32 + q*8 + m], sn1);
      }
      p2f[q*256 + i] = su0; p2f[q*256 + 128 + i] = su1;
      p4f[q*256 + i] = sn0; p4f[q*256 + 128 + i] = sn1;
    }
    __syncthreads();
    if (q < 2) {
      const float xo = xs[q][i];
      const float xa = pA[q*128+i] + pA[256+q*128+i] + pA[512+q*128+i] + pA[768+q*128+i];
      const float yy = pP[q*128+i] + pP[256+q*128+i] + pP[512+q*128+i] + pP[768+q*128+i];
      const float mm = pM[q*128+i] + pM[256+q*128+i] + pM[512+q*128+i] + pM[768+q*128+i];
      const float usv = p2f[q*128+i] + p2f[256+q*128+i] + p2f[512+q*128+i] + p2f[768+q*128+i];
      const float nsv = p4f[q*128+i] + p4f[256+q*128+i] + p4f[512+q*128+i] + p4f[768+q*128+i];
      TL[(size_t)(t+1)*(BB*DD) + (size_t)(b0 + q)*DD + i] = dt*yy + mm;
      xs[q][i] = xo + (xa + usv)*dt + sdt*nsv;
      lwloc -= 0.5f*dt*xo*yy;
    }
  }
  __syncthreads();
  {
    float g0 = 0.f, g1 = 0.f;
#pragma unroll
    for (int m = 0; m < 8; ++m) {
      const float4 qv = QL4[(q*8 + m)*128 + i];
      g0 = fma4(qv, xs4[q*8 + m], g0);
      g1 = fma4(qv, xs4[32 + q*8 + m], g1);
    }
    pA[q*256 + i] = g0; pA[q*256 + 128 + i] = g1;
  }
  __syncthreads();
  float qloc = 0.f;
  if (q < 2) {
    const float tt = pA[q*128+i] + pA[256+q*128+i] + pA[512+q*128+i] + pA[768+q*128+i];
    TGT[(b0 + q)*DD + i] = tt;
    qloc = xs[q][i]*tt;
  }
  const float rq = wave_red(qloc);
  const float rl = wave_red(lwloc);
  if ((tid & 63) == 0) { red[wid] = rq; red[8 + wid] = rl; }
  __syncthreads();
  if (tid < 2) {
    const float qf = red[2*tid] + red[2*tid + 1];
    const float lw = red[8 + 2*tid] + red[8 + 2*tid + 1];
    WGT[b0 + tid] = expf(lw - 0.5f*qf);
  }
}

// ---- suffix scan over t (64k independent scans) + fused objective (ident)
__global__ __launch_bounds__(256) void k_scan(
    const float* __restrict__ TGT, const float* __restrict__ WGT,
    const float* __restrict__ U, float* __restrict__ TL,
    const int* __restrict__ FLG, float* __restrict__ PART_S)
{
  const int tid = threadIdx.x;
  const int bi = blockIdx.x*256 + tid;
  const int b = bi >> 7;
  const bool id = (*FLG != 0);
  const float w = WGT[b];
  float lst = TGT[bi];
  float obj = 0.f;
  if (id) { const float d = lst + U[(size_t)NS*(BB*DD) + bi]; obj = w*d*d; }
#pragma unroll 4
  for (int t = NS; t >= 1; --t) {
    const float v = TL[(size_t)t*(BB*DD) + bi];
    if (!id) TL[(size_t)t*(BB*DD) + bi] = lst;
    lst += v;
    if (id) { const float d = lst + U[(size_t)(t-1)*(BB*DD) + bi]; obj += w*d*d; }
  }
  if (!id) TL[bi] = lst;
  __shared__ float r4[4];
  const float s = wave_red(obj);
  if ((tid & 63) == 0) r4[tid >> 6] = s;
  __syncthreads();
  if (tid == 0) PART_S[blockIdx.x] = id ? (r4[0]+r4[1]+r4[2]+r4[3]) : 0.f;
}

// ---- general-sigma objective (no-op when sigma == I)
__global__ __launch_bounds__(256) void k_obj(
    const float* __restrict__ SGC, const float* __restrict__ TL,
    const float* __restrict__ U, const float* __restrict__ WGT,
    const int* __restrict__ FLG, float* __restrict__ PART_O)
{
  const int blk = blockIdx.x;
  if (*FLG != 0) { if (threadIdx.x == 0) PART_O[blk] = 0.f; return; }
  const int t = blk >> 6, bg = blk & 63;
  __shared__ __align__(16) float ls[8][132];
  __shared__ __align__(16) float us[8][128];
  __shared__ __align__(16) float pD[2][8][128];
  __shared__ float wg[8];
  __shared__ float r4[4];
  const int tid = threadIdx.x;
  const int i = tid & 127, h = tid >> 7;
  for (int idx = tid; idx < 8*128; idx += 256) {
    const int rr = idx >> 7, k = idx & 127;
    ls[rr][k] = TL[(size_t)t*(BB*DD) + (size_t)(bg*8+rr)*DD + k];
    us[rr][k] = U [(size_t)t*(BB*DD) + (size_t)(bg*8+rr)*DD + k];
  }
  if (tid < 8) wg[tid] = WGT[bg*8 + tid];
  __syncthreads();
  const float* grow = SGC + i*DD + h*64;
#pragma unroll
  for (int rr = 0; rr < 8; ++rr) {
    float a = 0.f;
#pragma unroll
    for (int it = 0; it < 16; ++it) {
      float4 gv = *(const float4*)(grow + it*4);
      float4 l4 = *(const float4*)&ls[rr][h*64 + it*4];
      a = fma4(gv, l4, a);
    }
    pD[h][rr][i] = a;
  }
  __syncthreads();
  float obj = 0.f;
#pragma unroll
  for (int p = 0; p < 4; ++p) {
    const int rr = h*4 + p;
    const float d = pD[0][rr][i] + pD[1][rr][i] + us[rr][i];
    obj += wg[rr]*d*d;
  }
  const float s = wave_red(obj);
  if ((tid & 63) == 0) r4[tid >> 6] = s;
  __syncthreads();
  if (tid == 0) PART_O[blk] = r4[0]+r4[1]+r4[2]+r4[3];
}

__global__ __launch_bounds__(256) void k_fin(
    const float* __restrict__ PART_S, const float* __restrict__ PART_O,
    float* __restrict__ out)
{
  const int tid = threadIdx.x;
  float s = PART_S[tid];
  for (int idx = tid; idx < NPO; idx += 256) s += PART_O[idx];
  __shared__ float r4[4];
  const float v = wave_red(s);
  if ((tid & 63) == 0) r4[tid >> 6] = v;
  __syncthreads();
  if (tid == 0) out[0] = (r4[0]+r4[1]+r4[2]+r4[3]) * (1.0f/((float)(NS+1)*(float)BB));
}

extern "C" void kernel_launch(void* const* d_in, const int* in_sizes, int n_in,
                              void* d_out, int out_size, void* d_ws, size_t ws_size,
                              hipStream_t stream) {
  (void)in_sizes; (void)n_in; (void)out_size; (void)ws_size;
  const float* x0     = (const float*)d_in[0];
  const float* sigma  = (const float*)d_in[1];
  const float* A      = (const float*)d_in[2];
  const float* P      = (const float*)d_in[3];
  const float* Q      = (const float*)d_in[4];
  const float* W1     = (const float*)d_in[5];
  const float* b1     = (const float*)d_in[6];
  const float* W2     = (const float*)d_in[7];
  const float* b2     = (const float*)d_in[8];
  const float* noises = (const float*)d_in[9];

  float* ws = (float*)d_ws;
  const size_t SL_ = (size_t)BB*DD;
  float* TL     = ws;
  float* U      = TL + (size_t)(NS+1)*SL_;
  float* TGT    = U  + (size_t)(NS+1)*SL_;
  float* WGT    = TGT + SL_;
  float* W1Lw   = WGT + BB;
  float* W2Lw   = W1Lw + 32*256*4;
  float* ALm    = W2Lw + 64*128*4;
  float* PLm    = ALm + 32*128*4;
  float* MLm    = PLm + 32*128*4;
  float* SLm    = MLm + 32*128*4;
  float* STLm   = SLm + 32*128*4;
  float* QLm    = STLm + 32*128*4;
  float* W2ATLw = QLm + 32*128*4;
  float* Ab2w   = W2ATLw + 64*128*4;
  float* SGC    = Ab2w + DD;
  float* SIT    = SGC + (size_t)DD*DD;
  float* AUG    = SIT + (size_t)DD*DD;
  float* PART_S = AUG + (size_t)DD*256;
  float* PART_O = PART_S + 256;
  int*   FLG    = (int*)(PART_O + NPO);
  float* out    = (float*)d_out;

  k_pre1<<<1, 256, 0, stream>>>(sigma, SIT, AUG, FLG);
  k_pre2<<<256, 256, 0, stream>>>(W1, W2, A, P, Q, sigma, b2, SIT, FLG,
                                  W1Lw, W2Lw, ALm, PLm, MLm, SLm, STLm, QLm,
                                  W2ATLw, Ab2w, SGC);
  k_roll_id4w3<<<128, 512, 0, stream>>>(x0, W1, b1, b2, noises,
                                        W1Lw, W2Lw, W2ATLw, ALm, PLm, QLm,
                                        Ab2w, FLG, U, TL, TGT, WGT);
  k_roll_gen<<<256, 512, 0, stream>>>(x0, W1, b1, b2, noises,
                                      W1Lw, W2Lw, ALm, PLm, MLm, SLm, STLm, QLm,
                                      FLG, U, TL, TGT, WGT);
  k_scan<<<(BB*DD)/256, 256, 0, stream>>>(TGT, WGT, U, TL, FLG, PART_S);
  k_obj<<<NPO, 256, 0, stream>>>(SGC, TL, U, WGT, FLG, PART_O);
  k_fin<<<1, 256, 0, stream>>>(PART_S, PART_O, out);
}

// Round 18
// 1822.271 us; speedup vs baseline: 2.1521x; 2.1521x over previous
//
#include <hip/hip_runtime.h>
#include <math.h>

#define DD 128
#define HH 256
#define NS 300
#define BB 512
#define NPO (301*64)

__device__ __forceinline__ float tsf(int t){ return (float)((double)t*(1.0/(double)NS)); }

__device__ __forceinline__ float wave_red(float v){
#pragma unroll
  for(int o=32;o>0;o>>=1) v += __shfl_down(v,o);
  return v;
}
__device__ __forceinline__ float fma4(float4 a, float4 b, float acc){
  acc = fmaf(a.x,b.x,acc); acc = fmaf(a.y,b.y,acc);
  acc = fmaf(a.z,b.z,acc); acc = fmaf(a.w,b.w,acc); return acc;
}

// ---- pre1: identity flag + (general) Gauss-Jordan inverse -> SIT = sigma^-T
__global__ __launch_bounds__(256) void k_pre1(
    const float* __restrict__ sigma,
    float* __restrict__ SIT, float* __restrict__ AUG, int* __restrict__ FLG)
{
  const int j = threadIdx.x;
  __shared__ int s_ok; __shared__ int s_p; __shared__ float s_fac[DD];
  if (j == 0) s_ok = 1;
  __syncthreads();
  bool ok = true;
  for (int idx = j; idx < DD*DD; idx += 256) {
    const int r = idx >> 7, c = idx & 127;
    if (sigma[idx] != (r==c ? 1.f : 0.f)) ok = false;
  }
  if (!ok) s_ok = 0;
  __syncthreads();
  const bool ident = (s_ok != 0);
  if (j == 0) *FLG = ident ? 1 : 0;
  if (ident) {
    for (int idx = j; idx < DD*DD; idx += 256) {
      const int r = idx >> 7, c = idx & 127;
      SIT[idx] = (r==c) ? 1.f : 0.f;
    }
    return;
  }
  for (int idx = j; idx < DD*256; idx += 256) {
    const int r = idx >> 8, c = idx & 255;
    AUG[idx] = (c < DD) ? sigma[r*DD + c] : ((c-DD)==r ? 1.f : 0.f);
  }
  __syncthreads();
  for (int c = 0; c < DD; ++c) {
    if (j == 0) {
      int p = c; float best = fabsf(AUG[c*256 + c]);
      for (int r2 = c+1; r2 < DD; ++r2) {
        const float v = fabsf(AUG[r2*256 + c]);
        if (v > best) { best = v; p = r2; }
      }
      s_p = p;
    }
    __syncthreads();
    const int p = s_p;
    if (p != c) {
      const float tmp = AUG[c*256 + j];
      AUG[c*256 + j] = AUG[p*256 + j];
      AUG[p*256 + j] = tmp;
    }
    __syncthreads();
    const float pd = AUG[c*256 + c];
    const float rowv = AUG[c*256 + j];
    __syncthreads();
    AUG[c*256 + j] = rowv / pd;
    if (j < DD) s_fac[j] = (j == c) ? 0.f : AUG[j*256 + c];
    __syncthreads();
    const float prj = AUG[c*256 + j];
    for (int r2 = 0; r2 < DD; ++r2) {
      if (r2 != c) AUG[r2*256 + j] -= s_fac[r2] * prj;
    }
    __syncthreads();
  }
  for (int idx = j; idx < DD*DD; idx += 256) {
    const int j2 = idx >> 7, k = idx & 127;
    SIT[idx] = AUG[k*256 + DD + j2];   // sigma^-T[j2][k]
  }
}

// ---- pre2: quad-interleaved coalesced weight layouts (round-10)
__global__ __launch_bounds__(256) void k_pre2(
    const float* __restrict__ W1, const float* __restrict__ W2,
    const float* __restrict__ A, const float* __restrict__ P,
    const float* __restrict__ Q, const float* __restrict__ sigma,
    const float* __restrict__ SIT, const int* __restrict__ FLG,
    float* __restrict__ W1L, float* __restrict__ W2L,
    float* __restrict__ AL, float* __restrict__ PL,
    float* __restrict__ ML, float* __restrict__ SL,
    float* __restrict__ STL, float* __restrict__ QL,
    float* __restrict__ SGC)
{
  const int g = blockIdx.x*256 + threadIdx.x;
  const int gs = gridDim.x*256;
  const bool ident = (*FLG != 0);
  for (int idx = g; idx < 32*256; idx += gs) {
    const int k4 = idx >> 8, hj = idx & 255;
#pragma unroll
    for (int j = 0; j < 4; ++j)
      W1L[idx*4 + j] = W1[(4*k4 + 1 + j)*HH + hj];
  }
  for (int idx = g; idx < 64*128; idx += gs) {
    const int k4 = idx >> 7, i = idx & 127;
#pragma unroll
    for (int j = 0; j < 4; ++j)
      W2L[idx*4 + j] = W2[(4*k4 + j)*DD + i];
  }
  for (int idx = g; idx < 32*128; idx += gs) {
    const int k4 = idx >> 7, i = idx & 127;
#pragma unroll
    for (int j = 0; j < 4; ++j) {
      AL [idx*4 + j] = A[i*DD + 4*k4 + j];
      PL [idx*4 + j] = P[i*DD + 4*k4 + j];
      QL [idx*4 + j] = Q[i*DD + 4*k4 + j];
      STL[idx*4 + j] = sigma[i*DD + 4*k4 + j];
      SL [idx*4 + j] = sigma[(4*k4 + j)*DD + i];
      float m;
      if (ident) m = -A[i*DD + 4*k4 + j];
      else {
        float acc = 0.f;
        for (int jj = 0; jj < DD; ++jj)
          acc = fmaf(A[i*DD + jj], SIT[jj*DD + 4*k4 + j], acc);
        m = -acc;
      }
      ML[idx*4 + j] = m;
    }
  }
  for (int idx = g; idx < DD*DD; idx += gs) {
    const int i2 = idx >> 7, k = idx & 127;
    SGC[idx] = sigma[k*DD + i2];
  }
}

// ---- identity-sigma rollout: 128 blocks x 512 threads, 4 rows/block.
// Round-13 structure (the measured optimum of this family): 6 barriers/step,
// 390KB/step coalesced weight stream, 4x FLOPs per streamed byte, no
// register residency (128-VGPR budget), no phase folding (spills).
__global__ __launch_bounds__(512) void k_roll_id4(
    const float* __restrict__ x0,
    const float* __restrict__ W1, const float* __restrict__ b1,
    const float* __restrict__ b2, const float* __restrict__ noises,
    const float* __restrict__ W1L, const float* __restrict__ W2L,
    const float* __restrict__ AL, const float* __restrict__ PL,
    const float* __restrict__ QL, const int* __restrict__ FLG,
    float* __restrict__ U, float* __restrict__ TL,
    float* __restrict__ TGT, float* __restrict__ WGT)
{
  if (*FLG == 0) return;   // general sigma handled by k_roll_gen
  __shared__ __align__(16) float xs[4][128];
  __shared__ __align__(16) float hs[4][256];
  __shared__ __align__(16) float wv[4][128];
  __shared__ __align__(16) float p2[2][4][256];
  __shared__ __align__(16) float p4[4][4][128];
  __shared__ __align__(16) float pm3[3][4][4][128];
  __shared__ float red[16];

  const float4* W1L4 = (const float4*)W1L;
  const float4* W2L4 = (const float4*)W2L;
  const float4* AL4  = (const float4*)AL;
  const float4* PL4  = (const float4*)PL;
  const float4* QL4  = (const float4*)QL;
  float4* xs4 = (float4*)&xs[0][0];   // row r at quad offset r*32
  float4* hs4 = (float4*)&hs[0][0];   // row r at quad offset r*64
  float4* wv4 = (float4*)&wv[0][0];
  float* p4f = &p4[0][0][0];          // [g][r][128]
  float* pA  = &pm3[0][0][0][0];      // [g][r][128]
  float* pP  = &pm3[1][0][0][0];
  float* pM  = &pm3[2][0][0][0];

  const int tid = threadIdx.x;
  const int hj = tid & 255, hg = tid >> 8;   // layer-1 mapping
  const int i  = tid & 127, q  = tid >> 7;   // matvec quarter AND owned row
  const int wid = tid >> 6;
  const int b0 = blockIdx.x * 4;
  const float w1t = (hg == 0) ? W1[hj] : 0.f;
  const float b1c = b1[hj];
  const float b2i = b2[i];

  xs[q][i] = x0[i];   // all 4 rows start at x0

  float lwloc = 0.f, u_reg = 0.f, nz = 0.f;

  for (int t = 0; t <= NS; ++t) {
    __syncthreads();                                   // [A] xs ready
    const float t0 = tsf(t);
    const float dt = tsf(t+1) - t0;
    const float sdt = sqrtf(dt);
    nz = (t < NS) ? noises[((size_t)t*BB + b0 + q)*DD + i] : 0.f;

    // --- phase A: MLP layer-1 half-dot, 4 rows per W1 load
    {
      float a0 = t0*w1t, a1 = t0*w1t, a2 = t0*w1t, a3 = t0*w1t;
#pragma unroll
      for (int m = 0; m < 16; ++m) {
        const float4 w = W1L4[(hg*16 + m)*256 + hj];
        a0 = fma4(w, xs4[0*32 + hg*16 + m], a0);
        a1 = fma4(w, xs4[1*32 + hg*16 + m], a1);
        a2 = fma4(w, xs4[2*32 + hg*16 + m], a2);
        a3 = fma4(w, xs4[3*32 + hg*16 + m], a3);
      }
      p2[hg][0][hj] = a0; p2[hg][1][hj] = a1;
      p2[hg][2][hj] = a2; p2[hg][3][hj] = a3;
    }
    __syncthreads();                                   // [B]
    // --- phase B: tanh over 4x256 (2 per thread; same hidden col both)
    {
      const int rr = tid >> 8, cc = tid & 255;
      hs[rr][cc]     = tanhf(p2[0][rr][cc]     + p2[1][rr][cc]     + b1c);
      hs[rr + 2][cc] = tanhf(p2[0][rr + 2][cc] + p2[1][rr + 2][cc] + b1c);
    }
    __syncthreads();                                   // [C]
    // --- phase C: MLP layer-2 quarter-dot, 4 rows per W2 load
    {
      float c0 = 0.f, c1 = 0.f, c2 = 0.f, c3 = 0.f;
#pragma unroll
      for (int m = 0; m < 16; ++m) {
        const float4 w2 = W2L4[(q*16 + m)*128 + i];
        c0 = fma4(w2, hs4[0*64 + q*16 + m], c0);
        c1 = fma4(w2, hs4[1*64 + q*16 + m], c1);
        c2 = fma4(w2, hs4[2*64 + q*16 + m], c2);
        c3 = fma4(w2, hs4[3*64 + q*16 + m], c3);
      }
      p4f[q*512 + 0*128 + i] = c0; p4f[q*512 + 1*128 + i] = c1;
      p4f[q*512 + 2*128 + i] = c2; p4f[q*512 + 3*128 + i] = c3;
    }
    __syncthreads();                                   // [D]
    // --- phase D: owner (i, row q): nv -> u -> U store -> wv
    {
      const float nv = p4f[0*512 + q*128 + i] + p4f[1*512 + q*128 + i]
                     + p4f[2*512 + q*128 + i] + p4f[3*512 + q*128 + i] + b2i;
      u_reg = -nv;
      U[((size_t)t*BB + b0 + q)*DD + i] = u_reg;
      if (t < NS) {
        wv[q][i] = sdt*nz + dt*u_reg;
        lwloc += sdt*u_reg*nz - 0.5f*dt*u_reg*u_reg;
      }
    }
    if (t == NS) break;
    __syncthreads();                                   // [E] wv ready
    // --- phase E: A@x, P@x, A@wv quarter partials, 4 rows per load pair
    {
      float aA[4] = {0,0,0,0}, aP_[4] = {0,0,0,0}, aM[4] = {0,0,0,0};
#pragma unroll
      for (int m = 0; m < 8; ++m) {
        const float4 av = AL4[(q*8 + m)*128 + i];
        const float4 pv = PL4[(q*8 + m)*128 + i];
#pragma unroll
        for (int r = 0; r < 4; ++r) {
          const float4 xv = xs4[r*32 + q*8 + m];
          const float4 wvv = wv4[r*32 + q*8 + m];
          aA[r] = fma4(av, xv, aA[r]);
          aP_[r] = fma4(pv, xv, aP_[r]);
          aM[r] = fma4(av, wvv, aM[r]);
        }
      }
#pragma unroll
      for (int r = 0; r < 4; ++r) {
        pA[q*512 + r*128 + i] = aA[r];
        pP[q*512 + r*128 + i] = aP_[r];
        pM[q*512 + r*128 + i] = aM[r];
      }
    }
    __syncthreads();                                   // [F]
    // --- phase F: owner (i, row q) combine + TL store + x update
    {
      const float xo = xs[q][i];
      const float xa = pA[0*512 + q*128 + i] + pA[1*512 + q*128 + i]
                     + pA[2*512 + q*128 + i] + pA[3*512 + q*128 + i];
      const float yy = pP[0*512 + q*128 + i] + pP[1*512 + q*128 + i]
                     + pP[2*512 + q*128 + i] + pP[3*512 + q*128 + i];
      const float mm = -(pM[0*512 + q*128 + i] + pM[1*512 + q*128 + i]
                       + pM[2*512 + q*128 + i] + pM[3*512 + q*128 + i]);
      TL[(size_t)(t+1)*(BB*DD) + (size_t)(b0 + q)*DD + i] = dt*yy + mm;
      xs[q][i] = xo + (xa + u_reg)*dt + sdt*nz;
      lwloc -= 0.5f*dt*xo*yy;
    }
  }
  // --- epilogue: TGT = x_NS @ Q^T, WGT = exp(lw - 0.5 x^T Q x)
  __syncthreads();
  {
    float g0 = 0.f, g1 = 0.f, g2 = 0.f, g3 = 0.f;
#pragma unroll
    for (int m = 0; m < 8; ++m) {
      const float4 qv = QL4[(q*8 + m)*128 + i];
      g0 = fma4(qv, xs4[0*32 + q*8 + m], g0);
      g1 = fma4(qv, xs4[1*32 + q*8 + m], g1);
      g2 = fma4(qv, xs4[2*32 + q*8 + m], g2);
      g3 = fma4(qv, xs4[3*32 + q*8 + m], g3);
    }
    pA[q*512 + 0*128 + i] = g0; pA[q*512 + 1*128 + i] = g1;
    pA[q*512 + 2*128 + i] = g2; pA[q*512 + 3*128 + i] = g3;
  }
  __syncthreads();
  float qloc;
  {
    const float tt = pA[0*512 + q*128 + i] + pA[1*512 + q*128 + i]
                   + pA[2*512 + q*128 + i] + pA[3*512 + q*128 + i];
    TGT[(b0 + q)*DD + i] = tt;
    qloc = xs[q][i]*tt;
  }
  const float rq = wave_red(qloc);
  const float rl = wave_red(lwloc);
  if ((tid & 63) == 0) { red[wid] = rq; red[8 + wid] = rl; }
  __syncthreads();
  if (tid < 4) {
    const float qf = red[2*tid] + red[2*tid + 1];
    const float lw = red[8 + 2*tid] + red[8 + 2*tid + 1];
    WGT[b0 + tid] = expf(lw - 0.5f*qf);
  }
}

// ---- general-sigma rollout (round-10 structure, guarded; runs only if !ident)
__global__ __launch_bounds__(512) void k_roll_gen(
    const float* __restrict__ x0,
    const float* __restrict__ W1, const float* __restrict__ b1,
    const float* __restrict__ b2, const float* __restrict__ noises,
    const float* __restrict__ W1L, const float* __restrict__ W2L,
    const float* __restrict__ AL, const float* __restrict__ PL,
    const float* __restrict__ ML, const float* __restrict__ SL,
    const float* __restrict__ STL, const float* __restrict__ QL,
    const int* __restrict__ FLG,
    float* __restrict__ U, float* __restrict__ TL,
    float* __restrict__ TGT, float* __restrict__ WGT)
{
  if (*FLG != 0) return;
  __shared__ __align__(16) float xs[2][128];
  __shared__ __align__(16) float hs[2][256];
  __shared__ __align__(16) float noi[2][128];
  __shared__ __align__(16) float nvs[2][128];
  __shared__ __align__(16) float uu[2][128];
  __shared__ __align__(16) float wv[2][128];
  __shared__ __align__(16) float p2[2][2][256];
  __shared__ __align__(16) float p4[4][2][128];
  __shared__ __align__(16) float pm3[3][4][2][128];
  __shared__ float red[16];

  const float4* W1L4 = (const float4*)W1L;
  const float4* W2L4 = (const float4*)W2L;
  const float4* AL4  = (const float4*)AL;
  const float4* PL4  = (const float4*)PL;
  const float4* ML4  = (const float4*)ML;
  const float4* SL4  = (const float4*)SL;
  const float4* STL4 = (const float4*)STL;
  const float4* QL4  = (const float4*)QL;
  float4* xs4  = (float4*)&xs[0][0];
  float4* hs4  = (float4*)&hs[0][0];
  float4* wv4  = (float4*)&wv[0][0];
  float4* nvs4 = (float4*)&nvs[0][0];
  float4* uu4  = (float4*)&uu[0][0];
  float4* noi4 = (float4*)&noi[0][0];
  float* p2f = &p2[0][0][0];
  float* p4f = &p4[0][0][0];
  float* pA  = &pm3[0][0][0][0];
  float* pP  = &pm3[1][0][0][0];
  float* pM  = &pm3[2][0][0][0];

  const int tid = threadIdx.x;
  const int hj = tid & 255, hg = tid >> 8;
  const int i  = tid & 127, q  = tid >> 7;
  const int wid = tid >> 6;
  const int b0 = blockIdx.x * 2;
  const float w1t = (hg == 0) ? W1[hj] : 0.f;
  const float b1c = b1[hj];
  const float b2i = b2[i];

  if (tid < 256) xs[tid >> 7][tid & 127] = x0[tid & 127];

  float lwloc = 0.f, u_reg = 0.f, nz = 0.f;

  for (int t = 0; t <= NS; ++t) {
    __syncthreads();
    const float t0 = tsf(t);
    const float dt = tsf(t+1) - t0;
    const float sdt = sqrtf(dt);
    nz = 0.f;
    if (q < 2 && t < NS) {
      nz = noises[((size_t)t*BB + b0 + q)*DD + i];
      noi[q][i] = nz;
    }
    {
      float a0 = t0*w1t, a1 = t0*w1t;
#pragma unroll
      for (int m = 0; m < 16; ++m) {
        const float4 w = W1L4[(hg*16 + m)*256 + hj];
        a0 = fma4(w, xs4[hg*16 + m], a0);
        a1 = fma4(w, xs4[32 + hg*16 + m], a1);
      }
      p2[hg][0][hj] = a0; p2[hg][1][hj] = a1;
    }
    __syncthreads();
    {
      const int rr = tid >> 8, cc = tid & 255;
      hs[rr][cc] = tanhf(p2[0][rr][cc] + p2[1][rr][cc] + b1c);
    }
    __syncthreads();
    {
      float c0 = 0.f, c1 = 0.f;
#pragma unroll
      for (int m = 0; m < 16; ++m) {
        const float4 w2 = W2L4[(q*16 + m)*128 + i];
        c0 = fma4(w2, hs4[q*16 + m], c0);
        c1 = fma4(w2, hs4[64 + q*16 + m], c1);
      }
      p4[q][0][i] = c0; p4[q][1][i] = c1;
    }
    __syncthreads();
    if (q < 2) {
      nvs[q][i] = p4[0][q][i] + p4[1][q][i] + p4[2][q][i] + p4[3][q][i] + b2i;
    }
    __syncthreads();
    {
      float s0 = 0.f, s1 = 0.f;
#pragma unroll
      for (int m = 0; m < 8; ++m) {
        const float4 gv = SL4[(q*8 + m)*128 + i];
        s0 = fma4(gv, nvs4[q*8 + m], s0);
        s1 = fma4(gv, nvs4[32 + q*8 + m], s1);
      }
      pA[q*256 + i] = s0; pA[q*256 + 128 + i] = s1;
    }
    __syncthreads();
    if (q < 2) {
      u_reg = -(pA[q*128 + i] + pA[256 + q*128 + i]
              + pA[512 + q*128 + i] + pA[768 + q*128 + i]);
      uu[q][i] = u_reg;
      U[((size_t)t*BB + b0 + q)*DD + i] = u_reg;
      wv[q][i] = sdt*nz + dt*u_reg;
      if (t < NS) lwloc += sdt*u_reg*nz - 0.5f*dt*u_reg*u_reg;
    }
    if (t == NS) break;
    __syncthreads();
    {
      float aA0=0,aA1=0,aP0=0,aP1=0,aM0=0,aM1=0;
#pragma unroll
      for (int m = 0; m < 8; ++m) {
        const float4 av = AL4[(q*8 + m)*128 + i];
        const float4 pv = PL4[(q*8 + m)*128 + i];
        const float4 mv = ML4[(q*8 + m)*128 + i];
        const float4 x0v = xs4[q*8 + m];
        const float4 x1v = xs4[32 + q*8 + m];
        const float4 w0v = wv4[q*8 + m];
        const float4 w1v = wv4[32 + q*8 + m];
        aA0 = fma4(av, x0v, aA0); aA1 = fma4(av, x1v, aA1);
        aP0 = fma4(pv, x0v, aP0); aP1 = fma4(pv, x1v, aP1);
        aM0 = fma4(mv, w0v, aM0); aM1 = fma4(mv, w1v, aM1);
      }
      pA[q*256 + i] = aA0; pA[q*256 + 128 + i] = aA1;
      pP[q*256 + i] = aP0; pP[q*256 + 128 + i] = aP1;
      pM[q*256 + i] = aM0; pM[q*256 + 128 + i] = aM1;
      float su0=0,su1=0,sn0=0,sn1=0;
#pragma unroll
      for (int m = 0; m < 8; ++m) {
        const float4 sv = STL4[(q*8 + m)*128 + i];
        su0 = fma4(sv, uu4[q*8 + m],  su0);
        su1 = fma4(sv, uu4[32 + q*8 + m], su1);
        sn0 = fma4(sv, noi4[q*8 + m], sn0);
        sn1 = fma4(sv, noi4[32 + q*8 + m], sn1);
      }
      p2f[q*256 + i] = su0; p2f[q*256 + 128 + i] = su1;
      p4f[q*256 + i] = sn0; p4f[q*256 + 128 + i] = sn1;
    }
    __syncthreads();
    if (q < 2) {
      const float xo = xs[q][i];
      const float xa = pA[q*128+i] + pA[256+q*128+i] + pA[512+q*128+i] + pA[768+q*128+i];
      const float yy = pP[q*128+i] + pP[256+q*128+i] + pP[512+q*128+i] + pP[768+q*128+i];
      const float mm = pM[q*128+i] + pM[256+q*128+i] + pM[512+q*128+i] + pM[768+q*128+i];
      const float usv = p2f[q*128+i] + p2f[256+q*128+i] + p2f[512+q*128+i] + p2f[768+q*128+i];
      const float nsv = p4f[q*128+i] + p4f[256+q*128+i] + p4f[512+q*128+i] + p4f[768+q*128+i];
      TL[(size_t)(t+1)*(BB*DD) + (size_t)(b0 + q)*DD + i] = dt*yy + mm;
      xs[q][i] = xo + (xa + usv)*dt + sdt*nsv;
      lwloc -= 0.5f*dt*xo*yy;
    }
  }
  __syncthreads();
  {
    float g0 = 0.f, g1 = 0.f;
#pragma unroll
    for (int m = 0; m < 8; ++m) {
      const float4 qv = QL4[(q*8 + m)*128 + i];
      g0 = fma4(qv, xs4[q*8 + m], g0);
      g1 = fma4(qv, xs4[32 + q*8 + m], g1);
    }
    pA[q*256 + i] = g0; pA[q*256 + 128 + i] = g1;
  }
  __syncthreads();
  float qloc = 0.f;
  if (q < 2) {
    const float tt = pA[q*128+i] + pA[256+q*128+i] + pA[512+q*128+i] + pA[768+q*128+i];
    TGT[(b0 + q)*DD + i] = tt;
    qloc = xs[q][i]*tt;
  }
  const float rq = wave_red(qloc);
  const float rl = wave_red(lwloc);
  if ((tid & 63) == 0) { red[wid] = rq; red[8 + wid] = rl; }
  __syncthreads();
  if (tid < 2) {
    const float qf = red[2*tid] + red[2*tid + 1];
    const float lw = red[8 + 2*tid] + red[8 + 2*tid + 1];
    WGT[b0 + tid] = expf(lw - 0.5f*qf);
  }
}

// ---- suffix scan over t (64k independent scans) + fused objective (ident)
__global__ __launch_bounds__(256) void k_scan(
    const float* __restrict__ TGT, const float* __restrict__ WGT,
    const float* __restrict__ U, float* __restrict__ TL,
    const int* __restrict__ FLG, float* __restrict__ PART_S)
{
  const int tid = threadIdx.x;
  const int bi = blockIdx.x*256 + tid;
  const int b = bi >> 7;
  const bool id = (*FLG != 0);
  const float w = WGT[b];
  float lst = TGT[bi];
  float obj = 0.f;
  if (id) { const float d = lst + U[(size_t)NS*(BB*DD) + bi]; obj = w*d*d; }
#pragma unroll 4
  for (int t = NS; t >= 1; --t) {
    const float v = TL[(size_t)t*(BB*DD) + bi];
    if (!id) TL[(size_t)t*(BB*DD) + bi] = lst;
    lst += v;
    if (id) { const float d = lst + U[(size_t)(t-1)*(BB*DD) + bi]; obj += w*d*d; }
  }
  if (!id) TL[bi] = lst;
  __shared__ float r4[4];
  const float s = wave_red(obj);
  if ((tid & 63) == 0) r4[tid >> 6] = s;
  __syncthreads();
  if (tid == 0) PART_S[blockIdx.x] = id ? (r4[0]+r4[1]+r4[2]+r4[3]) : 0.f;
}

// ---- general-sigma objective (no-op when sigma == I)
__global__ __launch_bounds__(256) void k_obj(
    const float* __restrict__ SGC, const float* __restrict__ TL,
    const float* __restrict__ U, const float* __restrict__ WGT,
    const int* __restrict__ FLG, float* __restrict__ PART_O)
{
  const int blk = blockIdx.x;
  if (*FLG != 0) { if (threadIdx.x == 0) PART_O[blk] = 0.f; return; }
  const int t = blk >> 6, bg = blk & 63;
  __shared__ __align__(16) float ls[8][132];
  __shared__ __align__(16) float us[8][128];
  __shared__ __align__(16) float pD[2][8][128];
  __shared__ float wg[8];
  __shared__ float r4[4];
  const int tid = threadIdx.x;
  const int i = tid & 127, h = tid >> 7;
  for (int idx = tid; idx < 8*128; idx += 256) {
    const int rr = idx >> 7, k = idx & 127;
    ls[rr][k] = TL[(size_t)t*(BB*DD) + (size_t)(bg*8+rr)*DD + k];
    us[rr][k] = U [(size_t)t*(BB*DD) + (size_t)(bg*8+rr)*DD + k];
  }
  if (tid < 8) wg[tid] = WGT[bg*8 + tid];
  __syncthreads();
  const float* grow = SGC + i*DD + h*64;
#pragma unroll
  for (int rr = 0; rr < 8; ++rr) {
    float a = 0.f;
#pragma unroll
    for (int it = 0; it < 16; ++it) {
      float4 gv = *(const float4*)(grow + it*4);
      float4 l4 = *(const float4*)&ls[rr][h*64 + it*4];
      a = fma4(gv, l4, a);
    }
    pD[h][rr][i] = a;
  }
  __syncthreads();
  float obj = 0.f;
#pragma unroll
  for (int p = 0; p < 4; ++p) {
    const int rr = h*4 + p;
    const float d = pD[0][rr][i] + pD[1][rr][i] + us[rr][i];
    obj += wg[rr]*d*d;
  }
  const float s = wave_red(obj);
  if ((tid & 63) == 0) r4[tid >> 6] = s;
  __syncthreads();
  if (tid == 0) PART_O[blk] = r4[0]+r4[1]+r4[2]+r4[3];
}

__global__ __launch_bounds__(256) void k_fin(
    const float* __restrict__ PART_S, const float* __restrict__ PART_O,
    float* __restrict__ out)
{
  const int tid = threadIdx.x;
  float s = PART_S[tid];
  for (int idx = tid; idx < NPO; idx += 256) s += PART_O[idx];
  __shared__ float r4[4];
  const float v = wave_red(s);
  if ((tid & 63) == 0) r4[tid >> 6] = v;
  __syncthreads();
  if (tid == 0) out[0] = (r4[0]+r4[1]+r4[2]+r4[3]) * (1.0f/((float)(NS+1)*(float)BB));
}

extern "C" void kernel_launch(void* const* d_in, const int* in_sizes, int n_in,
                              void* d_out, int out_size, void* d_ws, size_t ws_size,
                              hipStream_t stream) {
  (void)in_sizes; (void)n_in; (void)out_size; (void)ws_size;
  const float* x0     = (const float*)d_in[0];
  const float* sigma  = (const float*)d_in[1];
  const float* A      = (const float*)d_in[2];
  const float* P      = (const float*)d_in[3];
  const float* Q      = (const float*)d_in[4];
  const float* W1     = (const float*)d_in[5];
  const float* b1     = (const float*)d_in[6];
  const float* W2     = (const float*)d_in[7];
  const float* b2     = (const float*)d_in[8];
  const float* noises = (const float*)d_in[9];

  float* ws = (float*)d_ws;
  const size_t SL_ = (size_t)BB*DD;
  float* TL     = ws;
  float* U      = TL + (size_t)(NS+1)*SL_;
  float* TGT    = U  + (size_t)(NS+1)*SL_;
  float* WGT    = TGT + SL_;
  float* W1Lw   = WGT + BB;
  float* W2Lw   = W1Lw + 32*256*4;
  float* ALm    = W2Lw + 64*128*4;
  float* PLm    = ALm + 32*128*4;
  float* MLm    = PLm + 32*128*4;
  float* SLm    = MLm + 32*128*4;
  float* STLm   = SLm + 32*128*4;
  float* QLm    = STLm + 32*128*4;
  float* SGC    = QLm + 32*128*4;
  float* SIT    = SGC + (size_t)DD*DD;
  float* AUG    = SIT + (size_t)DD*DD;
  float* PART_S = AUG + (size_t)DD*256;
  float* PART_O = PART_S + 256;
  int*   FLG    = (int*)(PART_O + NPO);
  float* out    = (float*)d_out;

  k_pre1<<<1, 256, 0, stream>>>(sigma, SIT, AUG, FLG);
  k_pre2<<<64, 256, 0, stream>>>(W1, W2, A, P, Q, sigma, SIT, FLG,
                                 W1Lw, W2Lw, ALm, PLm, MLm, SLm, STLm, QLm, SGC);
  k_roll_id4<<<128, 512, 0, stream>>>(x0, W1, b1, b2, noises,
                                      W1Lw, W2Lw, ALm, PLm, QLm, FLG,
                                      U, TL, TGT, WGT);
  k_roll_gen<<<256, 512, 0, stream>>>(x0, W1, b1, b2, noises,
                                      W1Lw, W2Lw, ALm, PLm, MLm, SLm, STLm, QLm,
                                      FLG, U, TL, TGT, WGT);
  k_scan<<<(BB*DD)/256, 256, 0, stream>>>(TGT, WGT, U, TL, FLG, PART_S);
  k_obj<<<NPO, 256, 0, stream>>>(SGC, TL, U, WGT, FLG, PART_O);
  k_fin<<<1, 256, 0, stream>>>(PART_S, PART_O, out);
}

// Round 19
// 1739.020 us; speedup vs baseline: 2.2552x; 1.0479x over previous
//
#include <hip/hip_runtime.h>
#include <math.h>

#define DD 128
#define HH 256
#define NS 300
#define BB 512
#define NPO (301*64)

// Dynamic-LDS float offsets for k_roll_id4l
#define L_XS   0        // [4][128]
#define L_HS   512      // [4][256]
#define L_WV   1536     // [4][128]
#define L_P2   2048     // [2][4][256]
#define L_P4   4096     // [4][4][128]
#define L_PM3  6144     // [3][4][4][128]
#define L_RED  12288    // 16
#define L_ALDS 12304    // 16384 floats: AL copy (64 KB), float4-aligned
#define L_FLOATS (12304 + 16384)
#define L_BYTES (L_FLOATS*4)   // 114,752 B

__device__ __forceinline__ float tsf(int t){ return (float)((double)t*(1.0/(double)NS)); }

__device__ __forceinline__ float wave_red(float v){
#pragma unroll
  for(int o=32;o>0;o>>=1) v += __shfl_down(v,o);
  return v;
}
__device__ __forceinline__ float fma4(float4 a, float4 b, float acc){
  acc = fmaf(a.x,b.x,acc); acc = fmaf(a.y,b.y,acc);
  acc = fmaf(a.z,b.z,acc); acc = fmaf(a.w,b.w,acc); return acc;
}

// ---- pre1: identity flag + (general) Gauss-Jordan inverse -> SIT = sigma^-T
__global__ __launch_bounds__(256) void k_pre1(
    const float* __restrict__ sigma,
    float* __restrict__ SIT, float* __restrict__ AUG, int* __restrict__ FLG)
{
  const int j = threadIdx.x;
  __shared__ int s_ok; __shared__ int s_p; __shared__ float s_fac[DD];
  if (j == 0) s_ok = 1;
  __syncthreads();
  bool ok = true;
  for (int idx = j; idx < DD*DD; idx += 256) {
    const int r = idx >> 7, c = idx & 127;
    if (sigma[idx] != (r==c ? 1.f : 0.f)) ok = false;
  }
  if (!ok) s_ok = 0;
  __syncthreads();
  const bool ident = (s_ok != 0);
  if (j == 0) *FLG = ident ? 1 : 0;
  if (ident) {
    for (int idx = j; idx < DD*DD; idx += 256) {
      const int r = idx >> 7, c = idx & 127;
      SIT[idx] = (r==c) ? 1.f : 0.f;
    }
    return;
  }
  for (int idx = j; idx < DD*256; idx += 256) {
    const int r = idx >> 8, c = idx & 255;
    AUG[idx] = (c < DD) ? sigma[r*DD + c] : ((c-DD)==r ? 1.f : 0.f);
  }
  __syncthreads();
  for (int c = 0; c < DD; ++c) {
    if (j == 0) {
      int p = c; float best = fabsf(AUG[c*256 + c]);
      for (int r2 = c+1; r2 < DD; ++r2) {
        const float v = fabsf(AUG[r2*256 + c]);
        if (v > best) { best = v; p = r2; }
      }
      s_p = p;
    }
    __syncthreads();
    const int p = s_p;
    if (p != c) {
      const float tmp = AUG[c*256 + j];
      AUG[c*256 + j] = AUG[p*256 + j];
      AUG[p*256 + j] = tmp;
    }
    __syncthreads();
    const float pd = AUG[c*256 + c];
    const float rowv = AUG[c*256 + j];
    __syncthreads();
    AUG[c*256 + j] = rowv / pd;
    if (j < DD) s_fac[j] = (j == c) ? 0.f : AUG[j*256 + c];
    __syncthreads();
    const float prj = AUG[c*256 + j];
    for (int r2 = 0; r2 < DD; ++r2) {
      if (r2 != c) AUG[r2*256 + j] -= s_fac[r2] * prj;
    }
    __syncthreads();
  }
  for (int idx = j; idx < DD*DD; idx += 256) {
    const int j2 = idx >> 7, k = idx & 127;
    SIT[idx] = AUG[k*256 + DD + j2];   // sigma^-T[j2][k]
  }
}

// ---- pre2: quad-interleaved coalesced weight layouts (round-10)
__global__ __launch_bounds__(256) void k_pre2(
    const float* __restrict__ W1, const float* __restrict__ W2,
    const float* __restrict__ A, const float* __restrict__ P,
    const float* __restrict__ Q, const float* __restrict__ sigma,
    const float* __restrict__ SIT, const int* __restrict__ FLG,
    float* __restrict__ W1L, float* __restrict__ W2L,
    float* __restrict__ AL, float* __restrict__ PL,
    float* __restrict__ ML, float* __restrict__ SL,
    float* __restrict__ STL, float* __restrict__ QL,
    float* __restrict__ SGC)
{
  const int g = blockIdx.x*256 + threadIdx.x;
  const int gs = gridDim.x*256;
  const bool ident = (*FLG != 0);
  for (int idx = g; idx < 32*256; idx += gs) {
    const int k4 = idx >> 8, hj = idx & 255;
#pragma unroll
    for (int j = 0; j < 4; ++j)
      W1L[idx*4 + j] = W1[(4*k4 + 1 + j)*HH + hj];
  }
  for (int idx = g; idx < 64*128; idx += gs) {
    const int k4 = idx >> 7, i = idx & 127;
#pragma unroll
    for (int j = 0; j < 4; ++j)
      W2L[idx*4 + j] = W2[(4*k4 + j)*DD + i];
  }
  for (int idx = g; idx < 32*128; idx += gs) {
    const int k4 = idx >> 7, i = idx & 127;
#pragma unroll
    for (int j = 0; j < 4; ++j) {
      AL [idx*4 + j] = A[i*DD + 4*k4 + j];
      PL [idx*4 + j] = P[i*DD + 4*k4 + j];
      QL [idx*4 + j] = Q[i*DD + 4*k4 + j];
      STL[idx*4 + j] = sigma[i*DD + 4*k4 + j];
      SL [idx*4 + j] = sigma[(4*k4 + j)*DD + i];
      float m;
      if (ident) m = -A[i*DD + 4*k4 + j];
      else {
        float acc = 0.f;
        for (int jj = 0; jj < DD; ++jj)
          acc = fmaf(A[i*DD + jj], SIT[jj*DD + 4*k4 + j], acc);
        m = -acc;
      }
      ML[idx*4 + j] = m;
    }
  }
  for (int idx = g; idx < DD*DD; idx += gs) {
    const int i2 = idx >> 7, k = idx & 127;
    SGC[idx] = sigma[k*DD + i2];
  }
}

// ---- identity-sigma rollout: 128 blocks x 512 threads, 4 rows/block.
// r13 structure + AL held in LDS (64 KB, copied once): phase E reads A from
// the LDS pipe while PL streams from L2 -> the two overlap, and the per-step
// L1-fill stream drops 394->330 KB. Register shapes identical to r13.
__global__ __launch_bounds__(512) void k_roll_id4l(
    const float* __restrict__ x0,
    const float* __restrict__ W1, const float* __restrict__ b1,
    const float* __restrict__ b2, const float* __restrict__ noises,
    const float* __restrict__ W1L, const float* __restrict__ W2L,
    const float* __restrict__ AL, const float* __restrict__ PL,
    const float* __restrict__ QL, const int* __restrict__ FLG,
    float* __restrict__ U, float* __restrict__ TL,
    float* __restrict__ TGT, float* __restrict__ WGT)
{
  if (*FLG == 0) return;   // general sigma handled by k_roll_gen
  extern __shared__ float sm[];
  float*  xs  = sm + L_XS;      // [r][128]
  float*  hs  = sm + L_HS;      // [r][256]
  float*  wv  = sm + L_WV;
  float*  p2  = sm + L_P2;      // [hg][r][256]
  float*  p4f = sm + L_P4;      // [g][r][128]
  float*  pm3 = sm + L_PM3;     // pA|pP|pM each [g][r][128]
  float*  red = sm + L_RED;
  float4* ALds4 = (float4*)(sm + L_ALDS);
  float4* xs4 = (float4*)xs;    // row r at quad offset r*32
  float4* hs4 = (float4*)hs;    // row r at quad offset r*64
  float4* wv4 = (float4*)wv;
  float*  pA = pm3, *pP = pm3 + 2048, *pM = pm3 + 4096;
  const float4* W1L4 = (const float4*)W1L;
  const float4* W2L4 = (const float4*)W2L;
  const float4* AL4  = (const float4*)AL;
  const float4* PL4  = (const float4*)PL;
  const float4* QL4  = (const float4*)QL;

  const int tid = threadIdx.x;
  const int hj = tid & 255, hg = tid >> 8;   // layer-1 mapping
  const int i  = tid & 127, q  = tid >> 7;   // matvec quarter AND owned row
  const int wid = tid >> 6;
  const int b0 = blockIdx.x * 4;
  const float w1t = (hg == 0) ? W1[hj] : 0.f;
  const float b1c = b1[hj];
  const float b2i = b2[i];

  // prologue: AL -> LDS (one coalesced copy), xs init
  for (int idx = tid; idx < 4096; idx += 512) ALds4[idx] = AL4[idx];
  xs[q*128 + i] = x0[i];

  float lwloc = 0.f, u_reg = 0.f, nz = 0.f;

  for (int t = 0; t <= NS; ++t) {
    __syncthreads();                                   // [A] xs (and ALds) ready
    const float t0 = tsf(t);
    const float dt = tsf(t+1) - t0;
    const float sdt = sqrtf(dt);
    nz = (t < NS) ? noises[((size_t)t*BB + b0 + q)*DD + i] : 0.f;

    // --- phase A: MLP layer-1 half-dot, 4 rows per W1 load
    {
      float a0 = t0*w1t, a1 = t0*w1t, a2 = t0*w1t, a3 = t0*w1t;
#pragma unroll
      for (int m = 0; m < 16; ++m) {
        const float4 w = W1L4[(hg*16 + m)*256 + hj];
        a0 = fma4(w, xs4[0*32 + hg*16 + m], a0);
        a1 = fma4(w, xs4[1*32 + hg*16 + m], a1);
        a2 = fma4(w, xs4[2*32 + hg*16 + m], a2);
        a3 = fma4(w, xs4[3*32 + hg*16 + m], a3);
      }
      p2[hg*1024 + 0*256 + hj] = a0; p2[hg*1024 + 1*256 + hj] = a1;
      p2[hg*1024 + 2*256 + hj] = a2; p2[hg*1024 + 3*256 + hj] = a3;
    }
    __syncthreads();                                   // [B]
    // --- phase B: tanh over 4x256 (2 per thread)
    {
      const int rr = tid >> 8, cc = tid & 255;
      hs[rr*256 + cc]       = tanhf(p2[rr*256 + cc]       + p2[1024 + rr*256 + cc]       + b1c);
      hs[(rr+2)*256 + cc]   = tanhf(p2[(rr+2)*256 + cc]   + p2[1024 + (rr+2)*256 + cc]   + b1c);
    }
    __syncthreads();                                   // [C]
    // --- phase C: MLP layer-2 quarter-dot, 4 rows per W2 load
    {
      float c0 = 0.f, c1 = 0.f, c2 = 0.f, c3 = 0.f;
#pragma unroll
      for (int m = 0; m < 16; ++m) {
        const float4 w2 = W2L4[(q*16 + m)*128 + i];
        c0 = fma4(w2, hs4[0*64 + q*16 + m], c0);
        c1 = fma4(w2, hs4[1*64 + q*16 + m], c1);
        c2 = fma4(w2, hs4[2*64 + q*16 + m], c2);
        c3 = fma4(w2, hs4[3*64 + q*16 + m], c3);
      }
      p4f[q*512 + 0*128 + i] = c0; p4f[q*512 + 1*128 + i] = c1;
      p4f[q*512 + 2*128 + i] = c2; p4f[q*512 + 3*128 + i] = c3;
    }
    __syncthreads();                                   // [D]
    // --- phase D: owner (i, row q): nv -> u -> U store -> wv
    {
      const float nv = p4f[0*512 + q*128 + i] + p4f[1*512 + q*128 + i]
                     + p4f[2*512 + q*128 + i] + p4f[3*512 + q*128 + i] + b2i;
      u_reg = -nv;
      U[((size_t)t*BB + b0 + q)*DD + i] = u_reg;
      if (t < NS) {
        wv[q*128 + i] = sdt*nz + dt*u_reg;
        lwloc += sdt*u_reg*nz - 0.5f*dt*u_reg*u_reg;
      }
    }
    if (t == NS) break;
    __syncthreads();                                   // [E] wv ready
    // --- phase E: A@x, P@x, A@wv quarter partials; A from LDS, P from L2
    {
      float aA[4] = {0,0,0,0}, aP_[4] = {0,0,0,0}, aM[4] = {0,0,0,0};
#pragma unroll
      for (int m = 0; m < 8; ++m) {
        const float4 av = ALds4[(q*8 + m)*128 + i];
        const float4 pv = PL4[(q*8 + m)*128 + i];
#pragma unroll
        for (int r = 0; r < 4; ++r) {
          const float4 xv = xs4[r*32 + q*8 + m];
          const float4 wvv = wv4[r*32 + q*8 + m];
          aA[r] = fma4(av, xv, aA[r]);
          aP_[r] = fma4(pv, xv, aP_[r]);
          aM[r] = fma4(av, wvv, aM[r]);
        }
      }
#pragma unroll
      for (int r = 0; r < 4; ++r) {
        pA[q*512 + r*128 + i] = aA[r];
        pP[q*512 + r*128 + i] = aP_[r];
        pM[q*512 + r*128 + i] = aM[r];
      }
    }
    __syncthreads();                                   // [F]
    // --- phase F: owner (i, row q) combine + TL store + x update
    {
      const float xo = xs[q*128 + i];
      const float xa = pA[0*512 + q*128 + i] + pA[1*512 + q*128 + i]
                     + pA[2*512 + q*128 + i] + pA[3*512 + q*128 + i];
      const float yy = pP[0*512 + q*128 + i] + pP[1*512 + q*128 + i]
                     + pP[2*512 + q*128 + i] + pP[3*512 + q*128 + i];
      const float mm = -(pM[0*512 + q*128 + i] + pM[1*512 + q*128 + i]
                       + pM[2*512 + q*128 + i] + pM[3*512 + q*128 + i]);
      TL[(size_t)(t+1)*(BB*DD) + (size_t)(b0 + q)*DD + i] = dt*yy + mm;
      xs[q*128 + i] = xo + (xa + u_reg)*dt + sdt*nz;
      lwloc -= 0.5f*dt*xo*yy;
    }
  }
  // --- epilogue: TGT = x_NS @ Q^T, WGT = exp(lw - 0.5 x^T Q x)
  __syncthreads();
  {
    float g0 = 0.f, g1 = 0.f, g2 = 0.f, g3 = 0.f;
#pragma unroll
    for (int m = 0; m < 8; ++m) {
      const float4 qv = QL4[(q*8 + m)*128 + i];
      g0 = fma4(qv, xs4[0*32 + q*8 + m], g0);
      g1 = fma4(qv, xs4[1*32 + q*8 + m], g1);
      g2 = fma4(qv, xs4[2*32 + q*8 + m], g2);
      g3 = fma4(qv, xs4[3*32 + q*8 + m], g3);
    }
    pA[q*512 + 0*128 + i] = g0; pA[q*512 + 1*128 + i] = g1;
    pA[q*512 + 2*128 + i] = g2; pA[q*512 + 3*128 + i] = g3;
  }
  __syncthreads();
  float qloc;
  {
    const float tt = pA[0*512 + q*128 + i] + pA[1*512 + q*128 + i]
                   + pA[2*512 + q*128 + i] + pA[3*512 + q*128 + i];
    TGT[(b0 + q)*DD + i] = tt;
    qloc = xs[q*128 + i]*tt;
  }
  const float rq = wave_red(qloc);
  const float rl = wave_red(lwloc);
  if ((tid & 63) == 0) { red[wid] = rq; red[8 + wid] = rl; }
  __syncthreads();
  if (tid < 4) {
    const float qf = red[2*tid] + red[2*tid + 1];
    const float lw = red[8 + 2*tid] + red[8 + 2*tid + 1];
    WGT[b0 + tid] = expf(lw - 0.5f*qf);
  }
}

// ---- general-sigma rollout (round-10 structure, guarded; runs only if !ident)
__global__ __launch_bounds__(512) void k_roll_gen(
    const float* __restrict__ x0,
    const float* __restrict__ W1, const float* __restrict__ b1,
    const float* __restrict__ b2, const float* __restrict__ noises,
    const float* __restrict__ W1L, const float* __restrict__ W2L,
    const float* __restrict__ AL, const float* __restrict__ PL,
    const float* __restrict__ ML, const float* __restrict__ SL,
    const float* __restrict__ STL, const float* __restrict__ QL,
    const int* __restrict__ FLG,
    float* __restrict__ U, float* __restrict__ TL,
    float* __restrict__ TGT, float* __restrict__ WGT)
{
  if (*FLG != 0) return;
  __shared__ __align__(16) float xs[2][128];
  __shared__ __align__(16) float hs[2][256];
  __shared__ __align__(16) float noi[2][128];
  __shared__ __align__(16) float nvs[2][128];
  __shared__ __align__(16) float uu[2][128];
  __shared__ __align__(16) float wv[2][128];
  __shared__ __align__(16) float p2[2][2][256];
  __shared__ __align__(16) float p4[4][2][128];
  __shared__ __align__(16) float pm3[3][4][2][128];
  __shared__ float red[16];

  const float4* W1L4 = (const float4*)W1L;
  const float4* W2L4 = (const float4*)W2L;
  const float4* AL4  = (const float4*)AL;
  const float4* PL4  = (const float4*)PL;
  const float4* ML4  = (const float4*)ML;
  const float4* SL4  = (const float4*)SL;
  const float4* STL4 = (const float4*)STL;
  const float4* QL4  = (const float4*)QL;
  float4* xs4  = (float4*)&xs[0][0];
  float4* hs4  = (float4*)&hs[0][0];
  float4* wv4  = (float4*)&wv[0][0];
  float4* nvs4 = (float4*)&nvs[0][0];
  float4* uu4  = (float4*)&uu[0][0];
  float4* noi4 = (float4*)&noi[0][0];
  float* p2f = &p2[0][0][0];
  float* p4f = &p4[0][0][0];
  float* pA  = &pm3[0][0][0][0];
  float* pP  = &pm3[1][0][0][0];
  float* pM  = &pm3[2][0][0][0];

  const int tid = threadIdx.x;
  const int hj = tid & 255, hg = tid >> 8;
  const int i  = tid & 127, q  = tid >> 7;
  const int wid = tid >> 6;
  const int b0 = blockIdx.x * 2;
  const float w1t = (hg == 0) ? W1[hj] : 0.f;
  const float b1c = b1[hj];
  const float b2i = b2[i];

  if (tid < 256) xs[tid >> 7][tid & 127] = x0[tid & 127];

  float lwloc = 0.f, u_reg = 0.f, nz = 0.f;

  for (int t = 0; t <= NS; ++t) {
    __syncthreads();
    const float t0 = tsf(t);
    const float dt = tsf(t+1) - t0;
    const float sdt = sqrtf(dt);
    nz = 0.f;
    if (q < 2 && t < NS) {
      nz = noises[((size_t)t*BB + b0 + q)*DD + i];
      noi[q][i] = nz;
    }
    {
      float a0 = t0*w1t, a1 = t0*w1t;
#pragma unroll
      for (int m = 0; m < 16; ++m) {
        const float4 w = W1L4[(hg*16 + m)*256 + hj];
        a0 = fma4(w, xs4[hg*16 + m], a0);
        a1 = fma4(w, xs4[32 + hg*16 + m], a1);
      }
      p2[hg][0][hj] = a0; p2[hg][1][hj] = a1;
    }
    __syncthreads();
    {
      const int rr = tid >> 8, cc = tid & 255;
      hs[rr][cc] = tanhf(p2[0][rr][cc] + p2[1][rr][cc] + b1c);
    }
    __syncthreads();
    {
      float c0 = 0.f, c1 = 0.f;
#pragma unroll
      for (int m = 0; m < 16; ++m) {
        const float4 w2 = W2L4[(q*16 + m)*128 + i];
        c0 = fma4(w2, hs4[q*16 + m], c0);
        c1 = fma4(w2, hs4[64 + q*16 + m], c1);
      }
      p4[q][0][i] = c0; p4[q][1][i] = c1;
    }
    __syncthreads();
    if (q < 2) {
      nvs[q][i] = p4[0][q][i] + p4[1][q][i] + p4[2][q][i] + p4[3][q][i] + b2i;
    }
    __syncthreads();
    {
      float s0 = 0.f, s1 = 0.f;
#pragma unroll
      for (int m = 0; m < 8; ++m) {
        const float4 gv = SL4[(q*8 + m)*128 + i];
        s0 = fma4(gv, nvs4[q*8 + m], s0);
        s1 = fma4(gv, nvs4[32 + q*8 + m], s1);
      }
      pA[q*256 + i] = s0; pA[q*256 + 128 + i] = s1;
    }
    __syncthreads();
    if (q < 2) {
      u_reg = -(pA[q*128 + i] + pA[256 + q*128 + i]
              + pA[512 + q*128 + i] + pA[768 + q*128 + i]);
      uu[q][i] = u_reg;
      U[((size_t)t*BB + b0 + q)*DD + i] = u_reg;
      wv[q][i] = sdt*nz + dt*u_reg;
      if (t < NS) lwloc += sdt*u_reg*nz - 0.5f*dt*u_reg*u_reg;
    }
    if (t == NS) break;
    __syncthreads();
    {
      float aA0=0,aA1=0,aP0=0,aP1=0,aM0=0,aM1=0;
#pragma unroll
      for (int m = 0; m < 8; ++m) {
        const float4 av = AL4[(q*8 + m)*128 + i];
        const float4 pv = PL4[(q*8 + m)*128 + i];
        const float4 mv = ML4[(q*8 + m)*128 + i];
        const float4 x0v = xs4[q*8 + m];
        const float4 x1v = xs4[32 + q*8 + m];
        const float4 w0v = wv4[q*8 + m];
        const float4 w1v = wv4[32 + q*8 + m];
        aA0 = fma4(av, x0v, aA0); aA1 = fma4(av, x1v, aA1);
        aP0 = fma4(pv, x0v, aP0); aP1 = fma4(pv, x1v, aP1);
        aM0 = fma4(mv, w0v, aM0); aM1 = fma4(mv, w1v, aM1);
      }
      pA[q*256 + i] = aA0; pA[q*256 + 128 + i] = aA1;
      pP[q*256 + i] = aP0; pP[q*256 + 128 + i] = aP1;
      pM[q*256 + i] = aM0; pM[q*256 + 128 + i] = aM1;
      float su0=0,su1=0,sn0=0,sn1=0;
#pragma unroll
      for (int m = 0; m < 8; ++m) {
        const float4 sv = STL4[(q*8 + m)*128 + i];
        su0 = fma4(sv, uu4[q*8 + m],  su0);
        su1 = fma4(sv, uu4[32 + q*8 + m], su1);
        sn0 = fma4(sv, noi4[q*8 + m], sn0);
        sn1 = fma4(sv, noi4[32 + q*8 + m], sn1);
      }
      p2f[q*256 + i] = su0; p2f[q*256 + 128 + i] = su1;
      p4f[q*256 + i] = sn0; p4f[q*256 + 128 + i] = sn1;
    }
    __syncthreads();
    if (q < 2) {
      const float xo = xs[q][i];
      const float xa = pA[q*128+i] + pA[256+q*128+i] + pA[512+q*128+i] + pA[768+q*128+i];
      const float yy = pP[q*128+i] + pP[256+q*128+i] + pP[512+q*128+i] + pP[768+q*128+i];
      const float mm = pM[q*128+i] + pM[256+q*128+i] + pM[512+q*128+i] + pM[768+q*128+i];
      const float usv = p2f[q*128+i] + p2f[256+q*128+i] + p2f[512+q*128+i] + p2f[768+q*128+i];
      const float nsv = p4f[q*128+i] + p4f[256+q*128+i] + p4f[512+q*128+i] + p4f[768+q*128+i];
      TL[(size_t)(t+1)*(BB*DD) + (size_t)(b0 + q)*DD + i] = dt*yy + mm;
      xs[q][i] = xo + (xa + usv)*dt + sdt*nsv;
      lwloc -= 0.5f*dt*xo*yy;
    }
  }
  __syncthreads();
  {
    float g0 = 0.f, g1 = 0.f;
#pragma unroll
    for (int m = 0; m < 8; ++m) {
      const float4 qv = QL4[(q*8 + m)*128 + i];
      g0 = fma4(qv, xs4[q*8 + m], g0);
      g1 = fma4(qv, xs4[32 + q*8 + m], g1);
    }
    pA[q*256 + i] = g0; pA[q*256 + 128 + i] = g1;
  }
  __syncthreads();
  float qloc = 0.f;
  if (q < 2) {
    const float tt = pA[q*128+i] + pA[256+q*128+i] + pA[512+q*128+i] + pA[768+q*128+i];
    TGT[(b0 + q)*DD + i] = tt;
    qloc = xs[q][i]*tt;
  }
  const float rq = wave_red(qloc);
  const float rl = wave_red(lwloc);
  if ((tid & 63) == 0) { red[wid] = rq; red[8 + wid] = rl; }
  __syncthreads();
  if (tid < 2) {
    const float qf = red[2*tid] + red[2*tid + 1];
    const float lw = red[8 + 2*tid] + red[8 + 2*tid + 1];
    WGT[b0 + tid] = expf(lw - 0.5f*qf);
  }
}

// ---- suffix scan over t (64k independent scans) + fused objective (ident)
__global__ __launch_bounds__(256) void k_scan(
    const float* __restrict__ TGT, const float* __restrict__ WGT,
    const float* __restrict__ U, float* __restrict__ TL,
    const int* __restrict__ FLG, float* __restrict__ PART_S)
{
  const int tid = threadIdx.x;
  const int bi = blockIdx.x*256 + tid;
  const int b = bi >> 7;
  const bool id = (*FLG != 0);
  const float w = WGT[b];
  float lst = TGT[bi];
  float obj = 0.f;
  if (id) { const float d = lst + U[(size_t)NS*(BB*DD) + bi]; obj = w*d*d; }
#pragma unroll 4
  for (int t = NS; t >= 1; --t) {
    const float v = TL[(size_t)t*(BB*DD) + bi];
    if (!id) TL[(size_t)t*(BB*DD) + bi] = lst;
    lst += v;
    if (id) { const float d = lst + U[(size_t)(t-1)*(BB*DD) + bi]; obj += w*d*d; }
  }
  if (!id) TL[bi] = lst;
  __shared__ float r4[4];
  const float s = wave_red(obj);
  if ((tid & 63) == 0) r4[tid >> 6] = s;
  __syncthreads();
  if (tid == 0) PART_S[blockIdx.x] = id ? (r4[0]+r4[1]+r4[2]+r4[3]) : 0.f;
}

// ---- general-sigma objective (no-op when sigma == I)
__global__ __launch_bounds__(256) void k_obj(
    const float* __restrict__ SGC, const float* __restrict__ TL,
    const float* __restrict__ U, const float* __restrict__ WGT,
    const int* __restrict__ FLG, float* __restrict__ PART_O)
{
  const int blk = blockIdx.x;
  if (*FLG != 0) { if (threadIdx.x == 0) PART_O[blk] = 0.f; return; }
  const int t = blk >> 6, bg = blk & 63;
  __shared__ __align__(16) float ls[8][132];
  __shared__ __align__(16) float us[8][128];
  __shared__ __align__(16) float pD[2][8][128];
  __shared__ float wg[8];
  __shared__ float r4[4];
  const int tid = threadIdx.x;
  const int i = tid & 127, h = tid >> 7;
  for (int idx = tid; idx < 8*128; idx += 256) {
    const int rr = idx >> 7, k = idx & 127;
    ls[rr][k] = TL[(size_t)t*(BB*DD) + (size_t)(bg*8+rr)*DD + k];
    us[rr][k] = U [(size_t)t*(BB*DD) + (size_t)(bg*8+rr)*DD + k];
  }
  if (tid < 8) wg[tid] = WGT[bg*8 + tid];
  __syncthreads();
  const float* grow = SGC + i*DD + h*64;
#pragma unroll
  for (int rr = 0; rr < 8; ++rr) {
    float a = 0.f;
#pragma unroll
    for (int it = 0; it < 16; ++it) {
      float4 gv = *(const float4*)(grow + it*4);
      float4 l4 = *(const float4*)&ls[rr][h*64 + it*4];
      a = fma4(gv, l4, a);
    }
    pD[h][rr][i] = a;
  }
  __syncthreads();
  float obj = 0.f;
#pragma unroll
  for (int p = 0; p < 4; ++p) {
    const int rr = h*4 + p;
    const float d = pD[0][rr][i] + pD[1][rr][i] + us[rr][i];
    obj += wg[rr]*d*d;
  }
  const float s = wave_red(obj);
  if ((tid & 63) == 0) r4[tid >> 6] = s;
  __syncthreads();
  if (tid == 0) PART_O[blk] = r4[0]+r4[1]+r4[2]+r4[3];
}

__global__ __launch_bounds__(256) void k_fin(
    const float* __restrict__ PART_S, const float* __restrict__ PART_O,
    float* __restrict__ out)
{
  const int tid = threadIdx.x;
  float s = PART_S[tid];
  for (int idx = tid; idx < NPO; idx += 256) s += PART_O[idx];
  __shared__ float r4[4];
  const float v = wave_red(s);
  if ((tid & 63) == 0) r4[tid >> 6] = v;
  __syncthreads();
  if (tid == 0) out[0] = (r4[0]+r4[1]+r4[2]+r4[3]) * (1.0f/((float)(NS+1)*(float)BB));
}

extern "C" void kernel_launch(void* const* d_in, const int* in_sizes, int n_in,
                              void* d_out, int out_size, void* d_ws, size_t ws_size,
                              hipStream_t stream) {
  (void)in_sizes; (void)n_in; (void)out_size; (void)ws_size;
  const float* x0     = (const float*)d_in[0];
  const float* sigma  = (const float*)d_in[1];
  const float* A      = (const float*)d_in[2];
  const float* P      = (const float*)d_in[3];
  const float* Q      = (const float*)d_in[4];
  const float* W1     = (const float*)d_in[5];
  const float* b1     = (const float*)d_in[6];
  const float* W2     = (const float*)d_in[7];
  const float* b2     = (const float*)d_in[8];
  const float* noises = (const float*)d_in[9];

  float* ws = (float*)d_ws;
  const size_t SL_ = (size_t)BB*DD;
  float* TL     = ws;
  float* U      = TL + (size_t)(NS+1)*SL_;
  float* TGT    = U  + (size_t)(NS+1)*SL_;
  float* WGT    = TGT + SL_;
  float* W1Lw   = WGT + BB;
  float* W2Lw   = W1Lw + 32*256*4;
  float* ALm    = W2Lw + 64*128*4;
  float* PLm    = ALm + 32*128*4;
  float* MLm    = PLm + 32*128*4;
  float* SLm    = MLm + 32*128*4;
  float* STLm   = SLm + 32*128*4;
  float* QLm    = STLm + 32*128*4;
  float* SGC    = QLm + 32*128*4;
  float* SIT    = SGC + (size_t)DD*DD;
  float* AUG    = SIT + (size_t)DD*DD;
  float* PART_S = AUG + (size_t)DD*256;
  float* PART_O = PART_S + 256;
  int*   FLG    = (int*)(PART_O + NPO);
  float* out    = (float*)d_out;

  (void)hipFuncSetAttribute((const void*)k_roll_id4l,
                            hipFuncAttributeMaxDynamicSharedMemorySize, L_BYTES);

  k_pre1<<<1, 256, 0, stream>>>(sigma, SIT, AUG, FLG);
  k_pre2<<<64, 256, 0, stream>>>(W1, W2, A, P, Q, sigma, SIT, FLG,
                                 W1Lw, W2Lw, ALm, PLm, MLm, SLm, STLm, QLm, SGC);
  k_roll_id4l<<<128, 512, L_BYTES, stream>>>(x0, W1, b1, b2, noises,
                                             W1Lw, W2Lw, ALm, PLm, QLm, FLG,
                                             U, TL, TGT, WGT);
  k_roll_gen<<<256, 512, 0, stream>>>(x0, W1, b1, b2, noises,
                                      W1Lw, W2Lw, ALm, PLm, MLm, SLm, STLm, QLm,
                                      FLG, U, TL, TGT, WGT);
  k_scan<<<(BB*DD)/256, 256, 0, stream>>>(TGT, WGT, U, TL, FLG, PART_S);
  k_obj<<<NPO, 256, 0, stream>>>(SGC, TL, U, WGT, FLG, PART_O);
  k_fin<<<1, 256, 0, stream>>>(PART_S, PART_O, out);
}